// Round 1
// baseline (291.932 us; speedup 1.0000x reference)
//
#include <hip/hip_runtime.h>
#include <math.h>

#define NB 4
#define NN 196
#define NC 64
#define ND0 800
#define NH 5
#define NO1 100
#define NC1 500   // heads*O1 = 5*100
#define NO2 64
#define TT 4
#define NEGF -1000000000.0f

// ---------------- K1: pl = transpose(latent) + positional encoding (f64 + f32 copies)
__global__ void k_pl(const float* __restrict__ latent, double* __restrict__ pl_d, float* __restrict__ pl_f) {
    int idx = blockIdx.x * blockDim.x + threadIdx.x;
    if (idx >= NB*NN*NC) return;
    int c = idx & (NC-1);
    int n = (idx >> 6) % NN;
    int b = idx / (NC*NN);
    int i = c >> 1;
    double div = exp((double)(2*i) * (-log(10000.0) / (double)NC));
    double ang = (double)n * div;
    double pe = (c & 1) ? cos(ang) : sin(ang);
    double v = (double)latent[(b*NC + c)*NN + n] + pe;
    pl_d[idx] = v;
    pl_f[idx] = (float)v;
}

// ---------------- K2: U[b,t,j] = pl[t]·w1[:64, j] ; VT[b,j,s] = pl[s]·w1[64:, j] + b1[j]  (f64)
__global__ void k_uv(const double* __restrict__ pl_d, const float* __restrict__ w1,
                     const float* __restrict__ b1, double* __restrict__ U, double* __restrict__ VT) {
    __shared__ double row[NC];
    int bn = blockIdx.x;           // b*NN+n
    int b = bn / NN, n = bn % NN;
    int tid = threadIdx.x;
    if (tid < NC) row[tid] = pl_d[bn*NC + tid];
    __syncthreads();
    for (int j = tid; j < ND0; j += blockDim.x) {
        double au = 0.0, av = (double)b1[j];
        #pragma unroll 8
        for (int k = 0; k < NC; ++k) {
            double p = row[k];
            au += p * (double)w1[k*ND0 + j];
            av += p * (double)w1[(NC + k)*ND0 + j];
        }
        U[(size_t)bn*ND0 + j] = au;
        VT[((size_t)b*ND0 + j)*NN + n] = av;
    }
}

// ---------------- K3: adj MLP + gumbel argmax -> WT[b][t_gat][s_gat] = weighted[b][s_gat][t_gat]
__global__ void k_adj(const double* __restrict__ U, const double* __restrict__ VT,
                      const float* __restrict__ w2, const float* __restrict__ b2,
                      const float* __restrict__ gum, float* __restrict__ WT) {
    __shared__ double Ul[TT][ND0];
    __shared__ double w2l[ND0];
    int bi = blockIdx.x;
    int b = bi / (NN/TT);
    int t0 = (bi % (NN/TT)) * TT;
    int tid = threadIdx.x;
    for (int idx = tid; idx < TT*ND0; idx += blockDim.x) {
        int tt = idx / ND0, j = idx % ND0;
        Ul[tt][j] = U[((size_t)(b*NN + t0 + tt))*ND0 + j];
    }
    for (int j = tid; j < ND0; j += blockDim.x) w2l[j] = (double)w2[j];
    __syncthreads();
    int s = tid;
    if (s >= NN) return;
    double bb2 = (double)b2[0];
    double acc0 = bb2, acc1 = bb2, acc2 = bb2, acc3 = bb2;
    for (int j = 0; j < ND0; ++j) {
        double v = VT[((size_t)b*ND0 + j)*NN + s];
        double w = w2l[j];
        double h0 = Ul[0][j] + v; h0 = (h0 >= 0.0) ? h0 : 0.01*h0; acc0 += h0*w;
        double h1 = Ul[1][j] + v; h1 = (h1 >= 0.0) ? h1 : 0.01*h1; acc1 += h1*w;
        double h2 = Ul[2][j] + v; h2 = (h2 >= 0.0) ? h2 : 0.01*h2; acc2 += h2*w;
        double h3 = Ul[3][j] + v; h3 = (h3 >= 0.0) ? h3 : 0.01*h3; acc3 += h3*w;
    }
    double acc[TT] = {acc0, acc1, acc2, acc3};
    for (int tt = 0; tt < TT; ++tt) {
        int t = t0 + tt;
        double adj = 1.0/(1.0 + exp(-acc[tt]));
        double l1 = log(fmax(adj, 1e-4));
        double l0 = log(fmax(1.0 - adj, 1e-4));
        double g0 = (double)gum[((size_t)(b*NN + t)*NN + s)*2 + 0];
        double g1 = (double)gum[((size_t)(b*NN + t)*NN + s)*2 + 1];
        double z0 = l0 + g0, z1 = l1 + g1;
        double m = fmax(z0, z1);
        double e0 = exp(z0 - m), e1 = exp(z1 - m);
        double sm = e0 + e1;
        int cg = (e1/sm) > (e0/sm);
        WT[((size_t)(b*NN + s))*NN + t] = cg ? (float)adj : 0.0f;
    }
}

// ---------------- K4: GAT1 projections xl1/xr1 = pl @ wl/wr + bl/br  (f32)
__global__ void k_proj1(const float* __restrict__ pl_f, const float* __restrict__ wl, const float* __restrict__ bl,
                        const float* __restrict__ wr, const float* __restrict__ br,
                        float* __restrict__ xl1, float* __restrict__ xr1) {
    __shared__ float row[NC];
    int bn = blockIdx.x;
    int tid = threadIdx.x;
    if (tid < NC) row[tid] = pl_f[bn*NC + tid];
    __syncthreads();
    for (int c = tid; c < NC1; c += blockDim.x) {
        float al = bl[c], ar = br[c];
        #pragma unroll 8
        for (int k = 0; k < NC; ++k) {
            float p = row[k];
            al += p * wl[k*NC1 + c];
            ar += p * wr[k*NC1 + c];
        }
        xl1[(size_t)bn*NC1 + c] = al;
        xr1[(size_t)bn*NC1 + c] = ar;
    }
}

// ---------------- K5: GAT1 attention per (b, target t) block; 5 heads
__global__ void k_gat1(const float* __restrict__ xl1, const float* __restrict__ xr1,
                       const float* __restrict__ WT, const float* __restrict__ we,
                       const float* __restrict__ att, const float* __restrict__ bias,
                       float* __restrict__ x1) {
    __shared__ float xr_l[NC1], we_l[NC1], at_l[NC1];
    __shared__ float wts[256];
    __shared__ float lg[NH*256];
    __shared__ float red[NH*256];
    __shared__ float mx[NH], sm[NH];
    int blk = blockIdx.x;
    int b = blk / NN, t = blk % NN;
    int tid = threadIdx.x;
    for (int c = tid; c < NC1; c += 256) {
        xr_l[c] = xr1[((size_t)(b*NN + t))*NC1 + c];
        we_l[c] = we[c];
        at_l[c] = att[c];
    }
    wts[tid] = (tid < NN) ? WT[((size_t)(b*NN + t))*NN + tid] : 0.0f;
    for (int idx = tid; idx < NH*256; idx += 256)
        if ((idx & 255) >= NN) lg[idx] = NEGF;
    __syncthreads();
    // logits per (s, h)
    for (int tau = tid; tau < NN*NH; tau += 256) {
        int s = tau / NH, h = tau % NH;
        float wt = wts[s];
        float acc = NEGF;
        if (wt != 0.0f) {
            acc = 0.0f;
            const float* xlr = xl1 + ((size_t)(b*NN + s))*NC1;
            int base = h*NO1;
            #pragma unroll 4
            for (int o = 0; o < NO1; ++o) {
                int c = base + o;
                float v = xlr[c] + xr_l[c] + wt*we_l[c];
                v = (v >= 0.0f) ? v : 0.2f*v;
                acc += v * at_l[c];
            }
        }
        lg[h*256 + s] = acc;
    }
    __syncthreads();
    for (int idx = tid; idx < NH*256; idx += 256) red[idx] = lg[idx];
    __syncthreads();
    for (int d = 128; d >= 1; d >>= 1) {
        if (tid < d)
            for (int h = 0; h < NH; ++h)
                red[h*256 + tid] = fmaxf(red[h*256 + tid], red[h*256 + tid + d]);
        __syncthreads();
    }
    if (tid < NH) mx[tid] = red[tid*256];
    __syncthreads();
    for (int idx = tid; idx < NH*256; idx += 256) {
        int h = idx >> 8, s = idx & 255;
        float e = 0.0f;
        if (s < NN && wts[s] != 0.0f) e = expf(lg[idx] - mx[h]);
        lg[idx] = e;
        red[idx] = e;
    }
    __syncthreads();
    for (int d = 128; d >= 1; d >>= 1) {
        if (tid < d)
            for (int h = 0; h < NH; ++h)
                red[h*256 + tid] += red[h*256 + tid + d];
        __syncthreads();
    }
    if (tid < NH) sm[tid] = red[tid*256];
    __syncthreads();
    for (int idx = tid; idx < NH*256; idx += 256) {
        int h = idx >> 8;
        lg[idx] = (sm[h] > 0.0f) ? lg[idx]/sm[h] : 0.0f;
    }
    __syncthreads();
    // aggregate: x1[t,c] = leaky( sum_s alpha[s,h(c)] * xl1[s,c] + bias[c], 0.01 )
    for (int c = tid; c < NC1; c += 256) {
        int h = c / NO1;
        float acc = 0.0f;
        for (int s = 0; s < NN; ++s)
            acc += lg[h*256 + s] * xl1[((size_t)(b*NN + s))*NC1 + c];
        float v = acc + bias[c];
        x1[((size_t)(b*NN + t))*NC1 + c] = (v >= 0.0f) ? v : 0.01f*v;
    }
}

// ---------------- K6: GAT2 head-0 projections: xl2/xr2 = x1 @ w[:, 0:64] + b[0:64]
__global__ void k_proj2(const float* __restrict__ x1, const float* __restrict__ wl, const float* __restrict__ bl,
                        const float* __restrict__ wr, const float* __restrict__ br,
                        float* __restrict__ xl2, float* __restrict__ xr2) {
    __shared__ float row[NC1];
    __shared__ float part[256];
    int bn = blockIdx.x;
    int tid = threadIdx.x;
    for (int c = tid; c < NC1; c += 256) row[c] = x1[(size_t)bn*NC1 + c];
    __syncthreads();
    int which = tid >> 7;          // 0: xl, 1: xr
    int o = tid & 63;
    int half = (tid >> 6) & 1;     // k-range split
    const float* w = which ? wr : wl;
    float acc = 0.0f;
    for (int k = half*250; k < half*250 + 250; ++k)
        acc += row[k] * w[(size_t)k*320 + o];
    part[tid] = acc;
    __syncthreads();
    if ((tid & 64) == 0) {
        float tot = part[tid] + part[tid + 64];
        if (which == 0) xl2[(size_t)bn*NO2 + o] = tot + bl[o];
        else            xr2[(size_t)bn*NO2 + o] = tot + br[o];
    }
}

// ---------------- K7: GAT2 head-0 attention + final channel softmax -> out
__global__ void k_gat2(const float* __restrict__ xl2, const float* __restrict__ xr2,
                       const float* __restrict__ WT, const float* __restrict__ we,
                       const float* __restrict__ att, const float* __restrict__ bias,
                       float* __restrict__ out) {
    __shared__ float xr_l[NO2], we_l[NO2], at_l[NO2], bi_l[NO2];
    __shared__ float wts[256], lg[256], red[256];
    __shared__ float mxs, sms;
    int blk = blockIdx.x;
    int b = blk / NN, t = blk % NN;
    int tid = threadIdx.x;
    if (tid < NO2) {
        xr_l[tid] = xr2[((size_t)(b*NN + t))*NO2 + tid];
        we_l[tid] = we[tid];
        at_l[tid] = att[tid];
        bi_l[tid] = bias[tid];
    }
    wts[tid] = (tid < NN) ? WT[((size_t)(b*NN + t))*NN + tid] : 0.0f;
    __syncthreads();
    float wt = wts[tid];
    float accl = NEGF;
    if (tid < NN && wt != 0.0f) {
        accl = 0.0f;
        const float* xlr = xl2 + ((size_t)(b*NN + tid))*NO2;
        #pragma unroll 4
        for (int o = 0; o < NO2; ++o) {
            float v = xlr[o] + xr_l[o] + wt*we_l[o];
            v = (v >= 0.0f) ? v : 0.2f*v;
            accl += v * at_l[o];
        }
    }
    lg[tid] = accl;
    red[tid] = accl;
    __syncthreads();
    for (int d = 128; d >= 1; d >>= 1) {
        if (tid < d) red[tid] = fmaxf(red[tid], red[tid + d]);
        __syncthreads();
    }
    if (tid == 0) mxs = red[0];
    __syncthreads();
    float e = (tid < NN && wt != 0.0f) ? expf(accl - mxs) : 0.0f;
    lg[tid] = e;
    red[tid] = e;
    __syncthreads();
    for (int d = 128; d >= 1; d >>= 1) {
        if (tid < d) red[tid] += red[tid + d];
        __syncthreads();
    }
    if (tid == 0) sms = red[0];
    __syncthreads();
    float alpha = (sms > 0.0f) ? lg[tid]/sms : 0.0f;
    lg[tid] = alpha;
    __syncthreads();
    if (tid < NO2) {
        float acc = 0.0f;
        for (int s = 0; s < NN; ++s)
            acc += lg[s] * xl2[((size_t)(b*NN + s))*NO2 + tid];
        float ny = acc + bi_l[tid];
        // softmax over the 64 channels (tid 0..63 = wave 0)
        float m = ny;
        for (int off = 32; off >= 1; off >>= 1) m = fmaxf(m, __shfl_xor(m, off));
        float ee = expf(ny - m);
        float ss = ee;
        for (int off = 32; off >= 1; off >>= 1) ss += __shfl_xor(ss, off);
        out[((size_t)(b*NN + t))*NO2 + tid] = ee / ss;
    }
}

extern "C" void kernel_launch(void* const* d_in, const int* in_sizes, int n_in,
                              void* d_out, int out_size, void* d_ws, size_t ws_size,
                              hipStream_t stream) {
    const float* latent  = (const float*)d_in[0];
    const float* gum     = (const float*)d_in[1];
    const float* d0_w1   = (const float*)d_in[2];
    const float* d0_b1   = (const float*)d_in[3];
    const float* d0_w2   = (const float*)d_in[4];
    const float* d0_b2   = (const float*)d_in[5];
    // d_in[6..11]: d1_* (dead: mask==0), a_w, a_b (dead: action node unused)
    const float* g1_wl   = (const float*)d_in[12];
    const float* g1_bl   = (const float*)d_in[13];
    const float* g1_wr   = (const float*)d_in[14];
    const float* g1_br   = (const float*)d_in[15];
    const float* g1_we   = (const float*)d_in[16];
    const float* g1_att  = (const float*)d_in[17];
    const float* g1_bias = (const float*)d_in[18];
    const float* g2_wl   = (const float*)d_in[19];
    const float* g2_bl   = (const float*)d_in[20];
    const float* g2_wr   = (const float*)d_in[21];
    const float* g2_br   = (const float*)d_in[22];
    const float* g2_we   = (const float*)d_in[23];
    const float* g2_att  = (const float*)d_in[24];
    const float* g2_bias = (const float*)d_in[25];
    float* out = (float*)d_out;

    char* ws = (char*)d_ws;
    size_t off = 0;
    auto alloc = [&](size_t bytes) { char* p = ws + off; off += (bytes + 255) & ~(size_t)255; return (void*)p; };
    double* pl_d = (double*)alloc((size_t)NB*NN*NC*8);
    float*  pl_f = (float*) alloc((size_t)NB*NN*NC*4);
    double* U_d  = (double*)alloc((size_t)NB*NN*ND0*8);
    double* VT_d = (double*)alloc((size_t)NB*ND0*NN*8);
    float*  WT   = (float*) alloc((size_t)NB*NN*NN*4);
    float*  xl1  = (float*) alloc((size_t)NB*NN*NC1*4);
    float*  xr1  = (float*) alloc((size_t)NB*NN*NC1*4);
    float*  x1   = (float*) alloc((size_t)NB*NN*NC1*4);
    float*  xl2  = (float*) alloc((size_t)NB*NN*NO2*4);
    float*  xr2  = (float*) alloc((size_t)NB*NN*NO2*4);

    hipLaunchKernelGGL(k_pl,    dim3((NB*NN*NC + 255)/256), dim3(256), 0, stream, latent, pl_d, pl_f);
    hipLaunchKernelGGL(k_uv,    dim3(NB*NN),        dim3(256), 0, stream, pl_d, d0_w1, d0_b1, U_d, VT_d);
    hipLaunchKernelGGL(k_adj,   dim3(NB*(NN/TT)),   dim3(256), 0, stream, U_d, VT_d, d0_w2, d0_b2, gum, WT);
    hipLaunchKernelGGL(k_proj1, dim3(NB*NN),        dim3(256), 0, stream, pl_f, g1_wl, g1_bl, g1_wr, g1_br, xl1, xr1);
    hipLaunchKernelGGL(k_gat1,  dim3(NB*NN),        dim3(256), 0, stream, xl1, xr1, WT, g1_we, g1_att, g1_bias, x1);
    hipLaunchKernelGGL(k_proj2, dim3(NB*NN),        dim3(256), 0, stream, x1, g2_wl, g2_bl, g2_wr, g2_br, xl2, xr2);
    hipLaunchKernelGGL(k_gat2,  dim3(NB*NN),        dim3(256), 0, stream, xl2, xr2, WT, g2_we, g2_att, g2_bias, out);
}

// Round 2
// 196.726 us; speedup vs baseline: 1.4840x; 1.4840x over previous
//
#include <hip/hip_runtime.h>
#include <math.h>

#define NB 4
#define NN 196
#define NC 64
#define ND0 800
#define NH 5
#define NO1 100
#define NC1 500   // heads*O1 = 5*100
#define NO2 64
#define TT 2      // targets per k_adj block
#define JC 4      // j-chunks per k_adj block
#define JW 200    // j per chunk (JC*JW == ND0)
#define NEGF -1000000000.0f

// ---------------- K1: pl = transpose(latent) + positional encoding (f64 + f32 copies)
__global__ void k_pl(const float* __restrict__ latent, double* __restrict__ pl_d, float* __restrict__ pl_f) {
    int idx = blockIdx.x * blockDim.x + threadIdx.x;
    if (idx >= NB*NN*NC) return;
    int c = idx & (NC-1);
    int n = (idx >> 6) % NN;
    int b = idx / (NC*NN);
    int i = c >> 1;
    double div = exp((double)(2*i) * (-log(10000.0) / (double)NC));
    double ang = (double)n * div;
    double pe = (c & 1) ? cos(ang) : sin(ang);
    double v = (double)latent[(b*NC + c)*NN + n] + pe;
    pl_d[idx] = v;
    pl_f[idx] = (float)v;
}

// ---------------- K2: U[b,t,j] = pl[t]·w1[:64, j] ; VT[b,j,s] = pl[s]·w1[64:, j] + b1[j]  (f64)
__global__ void k_uv(const double* __restrict__ pl_d, const float* __restrict__ w1,
                     const float* __restrict__ b1, double* __restrict__ U, double* __restrict__ VT) {
    __shared__ double row[NC];
    int bn = blockIdx.x;           // b*NN+n
    int b = bn / NN, n = bn % NN;
    int tid = threadIdx.x;
    if (tid < NC) row[tid] = pl_d[bn*NC + tid];
    __syncthreads();
    for (int j = tid; j < ND0; j += blockDim.x) {
        double au = 0.0, av = (double)b1[j];
        #pragma unroll 8
        for (int k = 0; k < NC; ++k) {
            double p = row[k];
            au += p * (double)w1[k*ND0 + j];
            av += p * (double)w1[(NC + k)*ND0 + j];
        }
        U[(size_t)bn*ND0 + j] = au;
        VT[((size_t)b*ND0 + j)*NN + n] = av;
    }
}

// ---------------- K3: adj MLP + gumbel argmax -> WT[b][t_gat][s_gat] = weighted[b][s_gat][t_gat]
// Block: (b, 2 targets), 1024 threads = 256 s-lanes x 4 j-chunks. LDS partial reduce.
__global__ void __launch_bounds__(1024)
k_adj(const double* __restrict__ U, const double* __restrict__ VT,
      const float* __restrict__ w2, const float* __restrict__ b2,
      const float* __restrict__ gum, float* __restrict__ WT) {
    __shared__ double Ul[TT][ND0];          // 12.8 KB
    __shared__ double w2l[ND0];             // 6.4 KB
    __shared__ double part[JC][TT][256];    // 16 KB
    int bi = blockIdx.x;
    int b = bi / (NN/TT);
    int t0 = (bi % (NN/TT)) * TT;
    int tid = threadIdx.x;                  // 0..1023
    int s = tid & 255;
    int chunk = tid >> 8;                   // 0..3
    for (int idx = tid; idx < TT*ND0; idx += 1024) {
        int tt = idx / ND0, j = idx - tt*ND0;
        Ul[tt][j] = U[((size_t)(b*NN + t0 + tt))*ND0 + j];
    }
    for (int j = tid; j < ND0; j += 1024) w2l[j] = (double)w2[j];
    __syncthreads();
    double a0 = 0.0, a1 = 0.0;
    if (s < NN) {
        const double* vp = VT + ((size_t)b*ND0 + chunk*JW)*NN + s;
        int j0 = chunk*JW;
        #pragma unroll 4
        for (int jj = 0; jj < JW; ++jj) {
            double v = vp[(size_t)jj*NN];
            double w = w2l[j0 + jj];
            double h0 = Ul[0][j0 + jj] + v; h0 = (h0 >= 0.0) ? h0 : 0.01*h0; a0 += h0*w;
            double h1 = Ul[1][j0 + jj] + v; h1 = (h1 >= 0.0) ? h1 : 0.01*h1; a1 += h1*w;
        }
    }
    part[chunk][0][s] = a0;
    part[chunk][1][s] = a1;
    __syncthreads();
    if (tid < TT*NN) {
        int tt = tid / NN, ss = tid - tt*NN;
        double acc = (double)b2[0] + part[0][tt][ss] + part[1][tt][ss]
                   + part[2][tt][ss] + part[3][tt][ss];
        int t = t0 + tt;
        double adj = 1.0/(1.0 + exp(-acc));
        double l1 = log(fmax(adj, 1e-4));
        double l0 = log(fmax(1.0 - adj, 1e-4));
        double g0 = (double)gum[((size_t)(b*NN + t)*NN + ss)*2 + 0];
        double g1 = (double)gum[((size_t)(b*NN + t)*NN + ss)*2 + 1];
        double z0 = l0 + g0, z1 = l1 + g1;
        double m = fmax(z0, z1);
        double e0 = exp(z0 - m), e1 = exp(z1 - m);
        double sm = e0 + e1;
        int cg = (e1/sm) > (e0/sm);
        WT[((size_t)(b*NN + ss))*NN + t] = cg ? (float)adj : 0.0f;
    }
}

// ---------------- K4: GAT1 projections xl1/xr1 = pl @ wl/wr + bl/br  (f32)
__global__ void k_proj1(const float* __restrict__ pl_f, const float* __restrict__ wl, const float* __restrict__ bl,
                        const float* __restrict__ wr, const float* __restrict__ br,
                        float* __restrict__ xl1, float* __restrict__ xr1) {
    __shared__ float row[NC];
    int bn = blockIdx.x;
    int tid = threadIdx.x;
    if (tid < NC) row[tid] = pl_f[bn*NC + tid];
    __syncthreads();
    for (int c = tid; c < NC1; c += blockDim.x) {
        float al = bl[c], ar = br[c];
        #pragma unroll 8
        for (int k = 0; k < NC; ++k) {
            float p = row[k];
            al += p * wl[k*NC1 + c];
            ar += p * wr[k*NC1 + c];
        }
        xl1[(size_t)bn*NC1 + c] = al;
        xr1[(size_t)bn*NC1 + c] = ar;
    }
}

// ---------------- K5: GAT1 attention per (b, target t) block; 5 heads
__global__ void k_gat1(const float* __restrict__ xl1, const float* __restrict__ xr1,
                       const float* __restrict__ WT, const float* __restrict__ we,
                       const float* __restrict__ att, const float* __restrict__ bias,
                       float* __restrict__ x1) {
    __shared__ float xr_l[NC1], we_l[NC1], at_l[NC1];
    __shared__ float wts[256];
    __shared__ float lg[NH*256];
    __shared__ float red[NH*256];
    __shared__ float mx[NH], sm[NH];
    int blk = blockIdx.x;
    int b = blk / NN, t = blk % NN;
    int tid = threadIdx.x;
    for (int c = tid; c < NC1; c += 256) {
        xr_l[c] = xr1[((size_t)(b*NN + t))*NC1 + c];
        we_l[c] = we[c];
        at_l[c] = att[c];
    }
    wts[tid] = (tid < NN) ? WT[((size_t)(b*NN + t))*NN + tid] : 0.0f;
    for (int idx = tid; idx < NH*256; idx += 256)
        if ((idx & 255) >= NN) lg[idx] = NEGF;
    __syncthreads();
    for (int tau = tid; tau < NN*NH; tau += 256) {
        int s = tau / NH, h = tau % NH;
        float wt = wts[s];
        float acc = NEGF;
        if (wt != 0.0f) {
            acc = 0.0f;
            const float* xlr = xl1 + ((size_t)(b*NN + s))*NC1;
            int base = h*NO1;
            #pragma unroll 4
            for (int o = 0; o < NO1; ++o) {
                int c = base + o;
                float v = xlr[c] + xr_l[c] + wt*we_l[c];
                v = (v >= 0.0f) ? v : 0.2f*v;
                acc += v * at_l[c];
            }
        }
        lg[h*256 + s] = acc;
    }
    __syncthreads();
    for (int idx = tid; idx < NH*256; idx += 256) red[idx] = lg[idx];
    __syncthreads();
    for (int d = 128; d >= 1; d >>= 1) {
        if (tid < d)
            for (int h = 0; h < NH; ++h)
                red[h*256 + tid] = fmaxf(red[h*256 + tid], red[h*256 + tid + d]);
        __syncthreads();
    }
    if (tid < NH) mx[tid] = red[tid*256];
    __syncthreads();
    for (int idx = tid; idx < NH*256; idx += 256) {
        int h = idx >> 8, s = idx & 255;
        float e = 0.0f;
        if (s < NN && wts[s] != 0.0f) e = expf(lg[idx] - mx[h]);
        lg[idx] = e;
        red[idx] = e;
    }
    __syncthreads();
    for (int d = 128; d >= 1; d >>= 1) {
        if (tid < d)
            for (int h = 0; h < NH; ++h)
                red[h*256 + tid] += red[h*256 + tid + d];
        __syncthreads();
    }
    if (tid < NH) sm[tid] = red[tid*256];
    __syncthreads();
    for (int idx = tid; idx < NH*256; idx += 256) {
        int h = idx >> 8;
        lg[idx] = (sm[h] > 0.0f) ? lg[idx]/sm[h] : 0.0f;
    }
    __syncthreads();
    for (int c = tid; c < NC1; c += 256) {
        int h = c / NO1;
        float acc = 0.0f;
        for (int s = 0; s < NN; ++s)
            acc += lg[h*256 + s] * xl1[((size_t)(b*NN + s))*NC1 + c];
        float v = acc + bias[c];
        x1[((size_t)(b*NN + t))*NC1 + c] = (v >= 0.0f) ? v : 0.01f*v;
    }
}

// ---------------- K6: GAT2 head-0 projections: xl2/xr2 = x1 @ w[:, 0:64] + b[0:64]
__global__ void k_proj2(const float* __restrict__ x1, const float* __restrict__ wl, const float* __restrict__ bl,
                        const float* __restrict__ wr, const float* __restrict__ br,
                        float* __restrict__ xl2, float* __restrict__ xr2) {
    __shared__ float row[NC1];
    __shared__ float part[256];
    int bn = blockIdx.x;
    int tid = threadIdx.x;
    for (int c = tid; c < NC1; c += 256) row[c] = x1[(size_t)bn*NC1 + c];
    __syncthreads();
    int which = tid >> 7;
    int o = tid & 63;
    int half = (tid >> 6) & 1;
    const float* w = which ? wr : wl;
    float acc = 0.0f;
    for (int k = half*250; k < half*250 + 250; ++k)
        acc += row[k] * w[(size_t)k*320 + o];
    part[tid] = acc;
    __syncthreads();
    if ((tid & 64) == 0) {
        float tot = part[tid] + part[tid + 64];
        if (which == 0) xl2[(size_t)bn*NO2 + o] = tot + bl[o];
        else            xr2[(size_t)bn*NO2 + o] = tot + br[o];
    }
}

// ---------------- K7: GAT2 head-0 attention + final channel softmax -> out
__global__ void k_gat2(const float* __restrict__ xl2, const float* __restrict__ xr2,
                       const float* __restrict__ WT, const float* __restrict__ we,
                       const float* __restrict__ att, const float* __restrict__ bias,
                       float* __restrict__ out) {
    __shared__ float xr_l[NO2], we_l[NO2], at_l[NO2], bi_l[NO2];
    __shared__ float wts[256], lg[256], red[256];
    __shared__ float mxs, sms;
    int blk = blockIdx.x;
    int b = blk / NN, t = blk % NN;
    int tid = threadIdx.x;
    if (tid < NO2) {
        xr_l[tid] = xr2[((size_t)(b*NN + t))*NO2 + tid];
        we_l[tid] = we[tid];
        at_l[tid] = att[tid];
        bi_l[tid] = bias[tid];
    }
    wts[tid] = (tid < NN) ? WT[((size_t)(b*NN + t))*NN + tid] : 0.0f;
    __syncthreads();
    float wt = wts[tid];
    float accl = NEGF;
    if (tid < NN && wt != 0.0f) {
        accl = 0.0f;
        const float* xlr = xl2 + ((size_t)(b*NN + tid))*NO2;
        #pragma unroll 4
        for (int o = 0; o < NO2; ++o) {
            float v = xlr[o] + xr_l[o] + wt*we_l[o];
            v = (v >= 0.0f) ? v : 0.2f*v;
            accl += v * at_l[o];
        }
    }
    lg[tid] = accl;
    red[tid] = accl;
    __syncthreads();
    for (int d = 128; d >= 1; d >>= 1) {
        if (tid < d) red[tid] = fmaxf(red[tid], red[tid + d]);
        __syncthreads();
    }
    if (tid == 0) mxs = red[0];
    __syncthreads();
    float e = (tid < NN && wt != 0.0f) ? expf(accl - mxs) : 0.0f;
    lg[tid] = e;
    red[tid] = e;
    __syncthreads();
    for (int d = 128; d >= 1; d >>= 1) {
        if (tid < d) red[tid] += red[tid + d];
        __syncthreads();
    }
    if (tid == 0) sms = red[0];
    __syncthreads();
    float alpha = (sms > 0.0f) ? lg[tid]/sms : 0.0f;
    lg[tid] = alpha;
    __syncthreads();
    if (tid < NO2) {
        float acc = 0.0f;
        for (int s = 0; s < NN; ++s)
            acc += lg[s] * xl2[((size_t)(b*NN + s))*NO2 + tid];
        float ny = acc + bi_l[tid];
        float m = ny;
        for (int off = 32; off >= 1; off >>= 1) m = fmaxf(m, __shfl_xor(m, off));
        float ee = expf(ny - m);
        float ss = ee;
        for (int off = 32; off >= 1; off >>= 1) ss += __shfl_xor(ss, off);
        out[((size_t)(b*NN + t))*NO2 + tid] = ee / ss;
    }
}

extern "C" void kernel_launch(void* const* d_in, const int* in_sizes, int n_in,
                              void* d_out, int out_size, void* d_ws, size_t ws_size,
                              hipStream_t stream) {
    const float* latent  = (const float*)d_in[0];
    const float* gum     = (const float*)d_in[1];
    const float* d0_w1   = (const float*)d_in[2];
    const float* d0_b1   = (const float*)d_in[3];
    const float* d0_w2   = (const float*)d_in[4];
    const float* d0_b2   = (const float*)d_in[5];
    const float* g1_wl   = (const float*)d_in[12];
    const float* g1_bl   = (const float*)d_in[13];
    const float* g1_wr   = (const float*)d_in[14];
    const float* g1_br   = (const float*)d_in[15];
    const float* g1_we   = (const float*)d_in[16];
    const float* g1_att  = (const float*)d_in[17];
    const float* g1_bias = (const float*)d_in[18];
    const float* g2_wl   = (const float*)d_in[19];
    const float* g2_bl   = (const float*)d_in[20];
    const float* g2_wr   = (const float*)d_in[21];
    const float* g2_br   = (const float*)d_in[22];
    const float* g2_we   = (const float*)d_in[23];
    const float* g2_att  = (const float*)d_in[24];
    const float* g2_bias = (const float*)d_in[25];
    float* out = (float*)d_out;

    char* ws = (char*)d_ws;
    size_t off = 0;
    auto alloc = [&](size_t bytes) { char* p = ws + off; off += (bytes + 255) & ~(size_t)255; return (void*)p; };
    double* pl_d = (double*)alloc((size_t)NB*NN*NC*8);
    float*  pl_f = (float*) alloc((size_t)NB*NN*NC*4);
    double* U_d  = (double*)alloc((size_t)NB*NN*ND0*8);
    double* VT_d = (double*)alloc((size_t)NB*ND0*NN*8);
    float*  WT   = (float*) alloc((size_t)NB*NN*NN*4);
    float*  xl1  = (float*) alloc((size_t)NB*NN*NC1*4);
    float*  xr1  = (float*) alloc((size_t)NB*NN*NC1*4);
    float*  x1   = (float*) alloc((size_t)NB*NN*NC1*4);
    float*  xl2  = (float*) alloc((size_t)NB*NN*NO2*4);
    float*  xr2  = (float*) alloc((size_t)NB*NN*NO2*4);

    hipLaunchKernelGGL(k_pl,    dim3((NB*NN*NC + 255)/256), dim3(256), 0, stream, latent, pl_d, pl_f);
    hipLaunchKernelGGL(k_uv,    dim3(NB*NN),        dim3(256),  0, stream, pl_d, d0_w1, d0_b1, U_d, VT_d);
    hipLaunchKernelGGL(k_adj,   dim3(NB*(NN/TT)),   dim3(1024), 0, stream, U_d, VT_d, d0_w2, d0_b2, gum, WT);
    hipLaunchKernelGGL(k_proj1, dim3(NB*NN),        dim3(256),  0, stream, pl_f, g1_wl, g1_bl, g1_wr, g1_br, xl1, xr1);
    hipLaunchKernelGGL(k_gat1,  dim3(NB*NN),        dim3(256),  0, stream, xl1, xr1, WT, g1_we, g1_att, g1_bias, x1);
    hipLaunchKernelGGL(k_proj2, dim3(NB*NN),        dim3(256),  0, stream, x1, g2_wl, g2_bl, g2_wr, g2_br, xl2, xr2);
    hipLaunchKernelGGL(k_gat2,  dim3(NB*NN),        dim3(256),  0, stream, xl2, xr2, WT, g2_we, g2_att, g2_bias, out);
}

// Round 3
// 195.148 us; speedup vs baseline: 1.4959x; 1.0081x over previous
//
#include <hip/hip_runtime.h>
#include <math.h>

#define NB 4
#define NN 196
#define NC 64
#define ND0 800
#define NH 5
#define NO1 100
#define NC1 500   // heads*O1 = 5*100
#define NO2 64
#define TT 2      // targets per k_adj block
#define JC 4      // j-chunks per k_adj block
#define JW 200    // j per chunk (JC*JW == ND0)
#define TQ 4      // targets per k_gat1b block
#define NEGF -1000000000.0f

// ---------------- K1: pl = transpose(latent) + positional encoding (f64 + f32 copies)
__global__ void k_pl(const float* __restrict__ latent, double* __restrict__ pl_d, float* __restrict__ pl_f) {
    int idx = blockIdx.x * blockDim.x + threadIdx.x;
    if (idx >= NB*NN*NC) return;
    int c = idx & (NC-1);
    int n = (idx >> 6) % NN;
    int b = idx / (NC*NN);
    int i = c >> 1;
    double div = exp((double)(2*i) * (-log(10000.0) / (double)NC));
    double ang = (double)n * div;
    double pe = (c & 1) ? cos(ang) : sin(ang);
    double v = (double)latent[(b*NC + c)*NN + n] + pe;
    pl_d[idx] = v;
    pl_f[idx] = (float)v;
}

// ---------------- K2: U[b,t,j] = pl[t]·w1[:64, j] ; VT[b,j,s] = pl[s]·w1[64:, j] + b1[j]  (f64)
__global__ void k_uv(const double* __restrict__ pl_d, const float* __restrict__ w1,
                     const float* __restrict__ b1, double* __restrict__ U, double* __restrict__ VT) {
    __shared__ double row[NC];
    int bn = blockIdx.x;           // b*NN+n
    int b = bn / NN, n = bn % NN;
    int tid = threadIdx.x;
    if (tid < NC) row[tid] = pl_d[bn*NC + tid];
    __syncthreads();
    for (int j = tid; j < ND0; j += blockDim.x) {
        double au = 0.0, av = (double)b1[j];
        #pragma unroll 8
        for (int k = 0; k < NC; ++k) {
            double p = row[k];
            au += p * (double)w1[k*ND0 + j];
            av += p * (double)w1[(NC + k)*ND0 + j];
        }
        U[(size_t)bn*ND0 + j] = au;
        VT[((size_t)b*ND0 + j)*NN + n] = av;
    }
}

// ---------------- K3: adj MLP + gumbel argmax -> WT[b][t_gat][s_gat] = weighted[b][s_gat][t_gat]
__global__ void __launch_bounds__(1024)
k_adj(const double* __restrict__ U, const double* __restrict__ VT,
      const float* __restrict__ w2, const float* __restrict__ b2,
      const float* __restrict__ gum, float* __restrict__ WT) {
    __shared__ double Ul[TT][ND0];
    __shared__ double w2l[ND0];
    __shared__ double part[JC][TT][256];
    int bi = blockIdx.x;
    int b = bi / (NN/TT);
    int t0 = (bi % (NN/TT)) * TT;
    int tid = threadIdx.x;
    int s = tid & 255;
    int chunk = tid >> 8;
    for (int idx = tid; idx < TT*ND0; idx += 1024) {
        int tt = idx / ND0, j = idx - tt*ND0;
        Ul[tt][j] = U[((size_t)(b*NN + t0 + tt))*ND0 + j];
    }
    for (int j = tid; j < ND0; j += 1024) w2l[j] = (double)w2[j];
    __syncthreads();
    double a0 = 0.0, a1 = 0.0;
    if (s < NN) {
        const double* vp = VT + ((size_t)b*ND0 + chunk*JW)*NN + s;
        int j0 = chunk*JW;
        #pragma unroll 4
        for (int jj = 0; jj < JW; ++jj) {
            double v = vp[(size_t)jj*NN];
            double w = w2l[j0 + jj];
            double h0 = Ul[0][j0 + jj] + v; h0 = (h0 >= 0.0) ? h0 : 0.01*h0; a0 += h0*w;
            double h1 = Ul[1][j0 + jj] + v; h1 = (h1 >= 0.0) ? h1 : 0.01*h1; a1 += h1*w;
        }
    }
    part[chunk][0][s] = a0;
    part[chunk][1][s] = a1;
    __syncthreads();
    if (tid < TT*NN) {
        int tt = tid / NN, ss = tid - tt*NN;
        double acc = (double)b2[0] + part[0][tt][ss] + part[1][tt][ss]
                   + part[2][tt][ss] + part[3][tt][ss];
        int t = t0 + tt;
        double adj = 1.0/(1.0 + exp(-acc));
        double l1 = log(fmax(adj, 1e-4));
        double l0 = log(fmax(1.0 - adj, 1e-4));
        double g0 = (double)gum[((size_t)(b*NN + t)*NN + ss)*2 + 0];
        double g1 = (double)gum[((size_t)(b*NN + t)*NN + ss)*2 + 1];
        double z0 = l0 + g0, z1 = l1 + g1;
        double m = fmax(z0, z1);
        double e0 = exp(z0 - m), e1 = exp(z1 - m);
        double sm = e0 + e1;
        int cg = (e1/sm) > (e0/sm);
        WT[((size_t)(b*NN + ss))*NN + t] = cg ? (float)adj : 0.0f;
    }
}

// ---------------- K4: GAT1 projections xl1/xl1T/xr1 = pl @ wl/wr + bl/br  (f32)
__global__ void k_proj1(const float* __restrict__ pl_f, const float* __restrict__ wl, const float* __restrict__ bl,
                        const float* __restrict__ wr, const float* __restrict__ br,
                        float* __restrict__ xl1, float* __restrict__ xl1T, float* __restrict__ xr1) {
    __shared__ float row[NC];
    int bn = blockIdx.x;
    int b = bn / NN, n = bn % NN;
    int tid = threadIdx.x;
    if (tid < NC) row[tid] = pl_f[bn*NC + tid];
    __syncthreads();
    for (int c = tid; c < NC1; c += blockDim.x) {
        float al = bl[c], ar = br[c];
        #pragma unroll 8
        for (int k = 0; k < NC; ++k) {
            float p = row[k];
            al += p * wl[k*NC1 + c];
            ar += p * wr[k*NC1 + c];
        }
        xl1[(size_t)bn*NC1 + c] = al;
        xr1[(size_t)bn*NC1 + c] = ar;
        xl1T[((size_t)b*NC1 + c)*256 + n] = al;
    }
}

// ---------------- K5a: GAT1 logits + softmax -> alphaG[b][h][t][s-pad256]
__global__ void __launch_bounds__(256)
k_gat1a(const float* __restrict__ xl1T, const float* __restrict__ xr1,
        const float* __restrict__ WT, const float* __restrict__ we,
        const float* __restrict__ att, float* __restrict__ alphaG) {
    __shared__ float red[NH][256];
    __shared__ float lgs[NH][256];
    __shared__ float mx[NH], sm[NH];
    int blk = blockIdx.x;
    int b = blk / NN, t = blk % NN;
    int s = threadIdx.x;
    float wt = (s < NN) ? WT[((size_t)(b*NN + t))*NN + s] : 0.0f;
    const float* xT = xl1T + (size_t)b*NC1*256;
    const float* xr = xr1 + ((size_t)(b*NN + t))*NC1;
    float accs[NH];
    #pragma unroll
    for (int h = 0; h < NH; ++h) {
        float a = 0.0f;
        for (int o = 0; o < NO1; ++o) {
            int c = h*NO1 + o;
            float x = xT[(size_t)c*256 + s];
            float v = fmaf(wt, we[c], x + xr[c]);
            float av = att[c];
            a += fmaxf(v, 0.0f)*av + fminf(v, 0.0f)*(0.2f*av);
        }
        accs[h] = a;
    }
    bool on = (s < NN) && (wt != 0.0f);
    #pragma unroll
    for (int h = 0; h < NH; ++h) {
        float l = on ? accs[h] : NEGF;
        lgs[h][s] = l; red[h][s] = l;
    }
    __syncthreads();
    for (int d = 128; d >= 1; d >>= 1) {
        if (s < d) {
            #pragma unroll
            for (int h = 0; h < NH; ++h)
                red[h][s] = fmaxf(red[h][s], red[h][s + d]);
        }
        __syncthreads();
    }
    if (s < NH) mx[s] = red[s][0];
    __syncthreads();
    #pragma unroll
    for (int h = 0; h < NH; ++h) {
        float e = on ? expf(lgs[h][s] - mx[h]) : 0.0f;
        lgs[h][s] = e; red[h][s] = e;
    }
    __syncthreads();
    for (int d = 128; d >= 1; d >>= 1) {
        if (s < d) {
            #pragma unroll
            for (int h = 0; h < NH; ++h)
                red[h][s] += red[h][s + d];
        }
        __syncthreads();
    }
    if (s < NH) sm[s] = red[s][0];
    __syncthreads();
    #pragma unroll
    for (int h = 0; h < NH; ++h) {
        float a = (sm[h] > 0.0f) ? lgs[h][s] / sm[h] : 0.0f;
        alphaG[(((size_t)b*NH + h)*NN + t)*256 + s] = a;
    }
}

// ---------------- K5b: GAT1 aggregate: x1[b,t,c] = leaky(sum_s alpha*xl1 + bias, 0.01)
// 640 threads = 10 waves: wave -> (h, c-subrange); 4 targets/block share xl1 loads.
__global__ void __launch_bounds__(640)
k_gat1b(const float* __restrict__ xl1, const float* __restrict__ alphaG,
        const float* __restrict__ bias, float* __restrict__ x1) {
    int blk = blockIdx.x;
    int b = blk / (NN/TQ), tq = blk % (NN/TQ);
    int tid = threadIdx.x;
    int w = tid >> 6, l = tid & 63;
    int h = w >> 1, csub = w & 1;
    int o = csub*64 + l;
    bool active = (o < NO1);
    int c = h*NO1 + (active ? o : 0);
    const float* ap = alphaG + (((size_t)b*NH + h)*NN + tq*TQ)*256;
    const float* xp = xl1 + (size_t)b*NN*NC1 + c;
    float a0 = 0.f, a1 = 0.f, a2 = 0.f, a3 = 0.f;
    for (int s = 0; s < NN; ++s) {
        float x = xp[(size_t)s*NC1];
        float p0 = ap[s], p1 = ap[256 + s], p2 = ap[512 + s], p3 = ap[768 + s];
        a0 = fmaf(p0, x, a0); a1 = fmaf(p1, x, a1);
        a2 = fmaf(p2, x, a2); a3 = fmaf(p3, x, a3);
    }
    if (active) {
        float bs = bias[c];
        float v;
        v = a0 + bs; x1[((size_t)(b*NN + tq*TQ + 0))*NC1 + c] = (v >= 0.f) ? v : 0.01f*v;
        v = a1 + bs; x1[((size_t)(b*NN + tq*TQ + 1))*NC1 + c] = (v >= 0.f) ? v : 0.01f*v;
        v = a2 + bs; x1[((size_t)(b*NN + tq*TQ + 2))*NC1 + c] = (v >= 0.f) ? v : 0.01f*v;
        v = a3 + bs; x1[((size_t)(b*NN + tq*TQ + 3))*NC1 + c] = (v >= 0.f) ? v : 0.01f*v;
    }
}

// ---------------- K6: GAT2 head-0 projections: xl2/xl2T/xr2 = x1 @ w[:, 0:64] + b[0:64]
__global__ void k_proj2(const float* __restrict__ x1, const float* __restrict__ wl, const float* __restrict__ bl,
                        const float* __restrict__ wr, const float* __restrict__ br,
                        float* __restrict__ xl2, float* __restrict__ xl2T, float* __restrict__ xr2) {
    __shared__ float row[NC1];
    __shared__ float part[256];
    int bn = blockIdx.x;
    int b = bn / NN, n = bn % NN;
    int tid = threadIdx.x;
    for (int c = tid; c < NC1; c += 256) row[c] = x1[(size_t)bn*NC1 + c];
    __syncthreads();
    int which = tid >> 7;
    int o = tid & 63;
    int half = (tid >> 6) & 1;
    const float* w = which ? wr : wl;
    float acc = 0.0f;
    for (int k = half*250; k < half*250 + 250; ++k)
        acc += row[k] * w[(size_t)k*320 + o];
    part[tid] = acc;
    __syncthreads();
    if ((tid & 64) == 0) {
        float tot = part[tid] + part[tid + 64];
        if (which == 0) {
            float v = tot + bl[o];
            xl2[(size_t)bn*NO2 + o] = v;
            xl2T[((size_t)b*NO2 + o)*256 + n] = v;
        } else {
            xr2[(size_t)bn*NO2 + o] = tot + br[o];
        }
    }
}

// ---------------- K7: GAT2 head-0 attention + final channel softmax -> out
__global__ void __launch_bounds__(256)
k_gat2(const float* __restrict__ xl2T, const float* __restrict__ xl2,
       const float* __restrict__ xr2, const float* __restrict__ WT,
       const float* __restrict__ we, const float* __restrict__ att,
       const float* __restrict__ bias, float* __restrict__ out) {
    __shared__ float red[256], alpha_l[256], part[4][NO2];
    __shared__ float mxs, sms;
    int blk = blockIdx.x;
    int b = blk / NN, t = blk % NN;
    int s = threadIdx.x;
    float wt = (s < NN) ? WT[((size_t)(b*NN + t))*NN + s] : 0.0f;
    const float* xT = xl2T + (size_t)b*NO2*256;
    const float* xr = xr2 + ((size_t)(b*NN + t))*NO2;
    float acc = 0.0f;
    for (int c = 0; c < NO2; ++c) {
        float x = xT[(size_t)c*256 + s];
        float v = fmaf(wt, we[c], x + xr[c]);
        float av = att[c];
        acc += fmaxf(v, 0.0f)*av + fminf(v, 0.0f)*(0.2f*av);
    }
    bool on = (s < NN) && (wt != 0.0f);
    float lgt = on ? acc : NEGF;
    red[s] = lgt;
    __syncthreads();
    for (int d = 128; d >= 1; d >>= 1) {
        if (s < d) red[s] = fmaxf(red[s], red[s + d]);
        __syncthreads();
    }
    if (s == 0) mxs = red[0];
    __syncthreads();
    float e = on ? expf(acc - mxs) : 0.0f;
    red[s] = e;
    __syncthreads();
    for (int d = 128; d >= 1; d >>= 1) {
        if (s < d) red[s] += red[s + d];
        __syncthreads();
    }
    if (s == 0) sms = red[0];
    __syncthreads();
    alpha_l[s] = (sms > 0.0f) ? e / sms : 0.0f;
    __syncthreads();
    int c = s & 63, sq = s >> 6;
    float pa = 0.0f;
    const float* xp = xl2 + (size_t)b*NN*NO2 + c;
    for (int ss = sq*49; ss < sq*49 + 49; ++ss)
        pa = fmaf(alpha_l[ss], xp[(size_t)ss*NO2], pa);
    part[sq][c] = pa;
    __syncthreads();
    if (s < NO2) {
        float ny = part[0][s] + part[1][s] + part[2][s] + part[3][s] + bias[s];
        float m = ny;
        for (int off = 32; off >= 1; off >>= 1) m = fmaxf(m, __shfl_xor(m, off));
        float ee = expf(ny - m);
        float ssum = ee;
        for (int off = 32; off >= 1; off >>= 1) ssum += __shfl_xor(ssum, off);
        out[((size_t)(b*NN + t))*NO2 + s] = ee / ssum;
    }
}

extern "C" void kernel_launch(void* const* d_in, const int* in_sizes, int n_in,
                              void* d_out, int out_size, void* d_ws, size_t ws_size,
                              hipStream_t stream) {
    const float* latent  = (const float*)d_in[0];
    const float* gum     = (const float*)d_in[1];
    const float* d0_w1   = (const float*)d_in[2];
    const float* d0_b1   = (const float*)d_in[3];
    const float* d0_w2   = (const float*)d_in[4];
    const float* d0_b2   = (const float*)d_in[5];
    const float* g1_wl   = (const float*)d_in[12];
    const float* g1_bl   = (const float*)d_in[13];
    const float* g1_wr   = (const float*)d_in[14];
    const float* g1_br   = (const float*)d_in[15];
    const float* g1_we   = (const float*)d_in[16];
    const float* g1_att  = (const float*)d_in[17];
    const float* g1_bias = (const float*)d_in[18];
    const float* g2_wl   = (const float*)d_in[19];
    const float* g2_bl   = (const float*)d_in[20];
    const float* g2_wr   = (const float*)d_in[21];
    const float* g2_br   = (const float*)d_in[22];
    const float* g2_we   = (const float*)d_in[23];
    const float* g2_att  = (const float*)d_in[24];
    const float* g2_bias = (const float*)d_in[25];
    float* out = (float*)d_out;

    char* ws = (char*)d_ws;
    size_t off = 0;
    auto alloc = [&](size_t bytes) { char* p = ws + off; off += (bytes + 255) & ~(size_t)255; return (void*)p; };
    double* pl_d  = (double*)alloc((size_t)NB*NN*NC*8);
    float*  pl_f  = (float*) alloc((size_t)NB*NN*NC*4);
    double* U_d   = (double*)alloc((size_t)NB*NN*ND0*8);
    double* VT_d  = (double*)alloc((size_t)NB*ND0*NN*8);
    float*  WT    = (float*) alloc((size_t)NB*NN*NN*4);
    float*  xl1   = (float*) alloc((size_t)NB*NN*NC1*4);
    float*  xl1T  = (float*) alloc((size_t)NB*NC1*256*4);
    float*  xr1   = (float*) alloc((size_t)NB*NN*NC1*4);
    float*  alphaG= (float*) alloc((size_t)NB*NH*NN*256*4);
    float*  x1    = (float*) alloc((size_t)NB*NN*NC1*4);
    float*  xl2   = (float*) alloc((size_t)NB*NN*NO2*4);
    float*  xl2T  = (float*) alloc((size_t)NB*NO2*256*4);
    float*  xr2   = (float*) alloc((size_t)NB*NN*NO2*4);

    hipLaunchKernelGGL(k_pl,     dim3((NB*NN*NC + 255)/256), dim3(256), 0, stream, latent, pl_d, pl_f);
    hipLaunchKernelGGL(k_uv,     dim3(NB*NN),       dim3(256),  0, stream, pl_d, d0_w1, d0_b1, U_d, VT_d);
    hipLaunchKernelGGL(k_adj,    dim3(NB*(NN/TT)),  dim3(1024), 0, stream, U_d, VT_d, d0_w2, d0_b2, gum, WT);
    hipLaunchKernelGGL(k_proj1,  dim3(NB*NN),       dim3(256),  0, stream, pl_f, g1_wl, g1_bl, g1_wr, g1_br, xl1, xl1T, xr1);
    hipLaunchKernelGGL(k_gat1a,  dim3(NB*NN),       dim3(256),  0, stream, xl1T, xr1, WT, g1_we, g1_att, alphaG);
    hipLaunchKernelGGL(k_gat1b,  dim3(NB*(NN/TQ)),  dim3(640),  0, stream, xl1, alphaG, g1_bias, x1);
    hipLaunchKernelGGL(k_proj2,  dim3(NB*NN),       dim3(256),  0, stream, x1, g2_wl, g2_bl, g2_wr, g2_br, xl2, xl2T, xr2);
    hipLaunchKernelGGL(k_gat2,   dim3(NB*NN),       dim3(256),  0, stream, xl2T, xl2, xr2, WT, g2_we, g2_att, g2_bias, out);
}